// Round 15
// baseline (1095.822 us; speedup 1.0000x reference)
//
#include <hip/hip_runtime.h>

#define NB 8
#define NP 4096
#define NS 1024
#define PROGSTRIDE 32   // one 128B cache line per cloud's progress word
#define XH_OFF 4150272          // f16 copy of x (4 MB), if ws_size allows
#define XH_BYTES (NB * NP * 64 * 2)

typedef _Float16 f16x8 __attribute__((ext_vector_type(8)));
typedef _Float16 f16x4 __attribute__((ext_vector_type(4)));
typedef float f32x4 __attribute__((ext_vector_type(4)));

// DPP-fused max step: v = max(v, dpp_move(v, ctrl)). bound_ctrl=false keeps
// old value on invalid lanes -> max(v,v)=v, harmless.
#define DPP_MAX(v, ctrl)                                                     \
    v = fmaxf(v, __int_as_float(__builtin_amdgcn_update_dpp(                 \
                __float_as_int(v), __float_as_int(v), (ctrl), 0xf, 0xf, false)))

struct PrepArgs {
    const float* src[9];
    _Float16* dst[9];
    int kr[9], kp[9], nc[9];
};

// ========================= Selection body ==========================
// Early-exit binary search on uint(d2) bits, no LDS staging, one center per
// wave. Bit-identical to exact top-k (tie path kept as fallback). FROZEN.
template <int K>
__device__ __forceinline__ void select_center(
        const float* __restrict__ pb,
        const float* __restrict__ centers,
        int* __restrict__ nbr, int* __restrict__ nvalid,
        float r2, int scid) {
#pragma clang fp contract(off)
    const int lane = threadIdx.x & 63;
    const unsigned kr2 = __float_as_uint(r2);
    const float cx = centers[scid * 3 + 0];
    const float cy = centers[scid * 3 + 1];
    const float cz = centers[scid * 3 + 2];

    unsigned key[64];
#pragma unroll
    for (int i = 0; i < 64; ++i) {
        const float* pp = pb + (size_t)(lane + i * 64) * 3;
        float dx = pp[0] - cx; float sx = dx * dx;
        float dy = pp[1] - cy; float sy = dy * dy;
        float dz = pp[2] - cz; float sz = dz * dz;
        float d2 = sx + sy; d2 = d2 + sz;
        key[i] = __float_as_uint(d2);
    }

    const unsigned long long below = (1ull << lane) - 1ull;
    int c_cnt = 0;
#pragma unroll
    for (int i = 0; i < 64; ++i)
        c_cnt += __popcll(__ballot(key[i] <= kr2));

    unsigned thr = kr2;          // threshold for the no-ties write pass
    int nv = c_cnt;
    bool need_ties = false;
    unsigned tkey = 0;
    if (c_cnt > K) {
        nv = K;
        unsigned lo = 0, hi = kr2;
        need_ties = true;
        while (lo < hi) {
            unsigned mid = lo + ((hi - lo) >> 1);
            int cnt = 0;
#pragma unroll
            for (int i = 0; i < 64; ++i)
                cnt += __popcll(__ballot(key[i] <= mid));
            if (cnt == K) { thr = mid; need_ties = false; break; }
            if (cnt > K) hi = mid; else lo = mid + 1;
        }
        tkey = lo;               // only meaningful if need_ties
    }

    if (!need_ties) {
        int base = 0;
#pragma unroll
        for (int i = 0; i < 64; ++i) {
            unsigned long long m = __ballot(key[i] <= thr);
            if (key[i] <= thr)
                nbr[(size_t)scid * K + base + __popcll(m & below)] = lane + i * 64;
            base += __popcll(m);
        }
    } else {
        const unsigned t = tkey;
        int m_cnt = 0;
#pragma unroll
        for (int i = 0; i < 64; ++i)
            m_cnt += __popcll(__ballot(key[i] < t));
        const int rem = K - m_cnt;
        int base = 0, tcnt = 0;
#pragma unroll
        for (int i = 0; i < 64; ++i) {
            unsigned long long lt = __ballot(key[i] < t);
            unsigned long long eq = __ballot(key[i] == t);
            if (key[i] < t) {
                nbr[(size_t)scid * K + base + __popcll(lt & below)] = lane + i * 64;
            } else if (key[i] == t) {
                int tr = tcnt + __popcll(eq & below);
                if (tr < rem) nbr[(size_t)scid * K + (m_cnt + tr)] = lane + i * 64;
            }
            base += __popcll(lt);
            tcnt += __popcll(eq);
        }
    }
    if (lane == 0) nvalid[scid] = nv;
}

// ================== FUSED FPS (producers) + SELECT (consumers) ==============
// MEASURED-GOOD (fused dispatch ~797-804us, six-times-stable). fps 8 blocks
// + 248 select worker blocks (1984 waves), prep (weights + xh) in worker
// preamble (spin shadow), padded prog lines, s_sleep(32), cadence-16
// publish. FROZEN — R3 (LDS cbuf), R5 (spin contention), R7/R9 (triple
// fusion) all measured neutral or worse.
// NOTE: fp contract(off) is REQUIRED — contraction perturbs d2 ulps and can
// flip FPS argmax near-ties -> different centers -> output blowup.
__global__ __launch_bounds__(512, 1) void fps_select_fused(
        const float* __restrict__ pos,
        float* __restrict__ centers,
        float* __restrict__ out_pos,
        float* __restrict__ out_batch,
        int* __restrict__ nbr0, int* __restrict__ nbr1, int* __restrict__ nbr2,
        int* __restrict__ nval,
        unsigned* __restrict__ prog,
        PrepArgs pa,
        const float* __restrict__ x,
        _Float16* __restrict__ xh) {
#pragma clang fp contract(off)
    const int tid = threadIdx.x;
    const int lane = tid & 63;

    if (blockIdx.x < NB) {
        // ------------------------ producer: FPS ------------------------
        const int b = blockIdx.x;
        const int wid = tid >> 6;
        __shared__ float4 slot[2][8];   // [parity][wave]

        const float* pb = pos + (size_t)b * NP * 3;
        float px[8], py[8], pz[8], md[8];
        {
            const float4* pv = (const float4*)(pb + tid * 24);
            float4 q0 = pv[0], q1 = pv[1], q2 = pv[2];
            float4 q3 = pv[3], q4 = pv[4], q5 = pv[5];
            px[0] = q0.x; py[0] = q0.y; pz[0] = q0.z;
            px[1] = q0.w; py[1] = q1.x; pz[1] = q1.y;
            px[2] = q1.z; py[2] = q1.w; pz[2] = q2.x;
            px[3] = q2.y; py[3] = q2.z; pz[3] = q2.w;
            px[4] = q3.x; py[4] = q3.y; pz[4] = q3.z;
            px[5] = q3.w; py[5] = q4.x; pz[5] = q4.y;
            px[6] = q4.z; py[6] = q4.w; pz[6] = q5.x;
            px[7] = q5.y; py[7] = q5.z; pz[7] = q5.w;
        }
#pragma unroll
        for (int j = 0; j < 8; ++j) md[j] = __builtin_inff();
        for (int t = tid; t < NS; t += 512) out_batch[b * NS + t] = (float)b;

        float cx = pb[0], cy = pb[1], cz = pb[2];
        if (tid == 0) {
            size_t o = (size_t)(b * NS) * 3;
            centers[o + 0] = cx; centers[o + 1] = cy; centers[o + 2] = cz;
            out_pos[o + 0] = cx; out_pos[o + 1] = cy; out_pos[o + 2] = cz;
        }

        int par = 0;
        for (int t = 1; t < NS; ++t) {
            float bv = -1.0f, bx = cx, by = cy, bz = cz;
#pragma unroll
            for (int j = 0; j < 8; ++j) {
                float dx = px[j] - cx; float sx = dx * dx;
                float dy = py[j] - cy; float sy = dy * dy;
                float dz = pz[j] - cz; float sz = dz * dz;
                float d = sx + sy; d = d + sz;
                float m = fminf(md[j], d);
                md[j] = m;
                bool c = m > bv;                 // strict >: first j wins ties
                bv = c ? m : bv;
                bx = c ? px[j] : bx;
                by = c ? py[j] : by;
                bz = c ? pz[j] : bz;
            }
            // wave max via DPP (result valid in lane 63), then SGPR broadcast
            float v = bv;
            DPP_MAX(v, 0x111);   // row_shr:1
            DPP_MAX(v, 0x112);   // row_shr:2
            DPP_MAX(v, 0x114);   // row_shr:4
            DPP_MAX(v, 0x118);   // row_shr:8
            DPP_MAX(v, 0x142);   // row_bcast:15
            DPP_MAX(v, 0x143);   // row_bcast:31
            const float mx = __int_as_float(
                __builtin_amdgcn_readlane(__float_as_int(v), 63));
            unsigned long long tie = __ballot(bv == mx);
            if (lane == __ffsll(tie) - 1)        // lowest lane among ties
                slot[par][wid] = make_float4(mx, bx, by, bz);
            __syncthreads();
            float4 s0 = slot[par][0], s1 = slot[par][1];
            float4 s2 = slot[par][2], s3 = slot[par][3];
            float4 s4 = slot[par][4], s5 = slot[par][5];
            float4 s6 = slot[par][6], s7 = slot[par][7];
            float4 a01 = (s1.x > s0.x) ? s1 : s0;   // ties keep lower wave
            float4 a23 = (s3.x > s2.x) ? s3 : s2;
            float4 a45 = (s5.x > s4.x) ? s5 : s4;
            float4 a67 = (s7.x > s6.x) ? s7 : s6;
            float4 b03 = (a23.x > a01.x) ? a23 : a01;
            float4 b47 = (a67.x > a45.x) ? a67 : a45;
            float4 wn = (b47.x > b03.x) ? b47 : b03;
            cx = wn.y; cy = wn.z; cz = wn.w;
            if (tid == 0) {
                size_t o = (size_t)(b * NS + t) * 3;
                centers[o + 0] = cx; centers[o + 1] = cy; centers[o + 2] = cz;
                out_pos[o + 0] = cx; out_pos[o + 1] = cy; out_pos[o + 2] = cz;
                if ((t & 15) == 15)   // cadence-16 publish; t=1023 -> 1024
                    __hip_atomic_store(&prog[b * PROGSTRIDE], (unsigned)(t + 1),
                                       __ATOMIC_RELEASE, __HIP_MEMORY_SCOPE_AGENT);
            }
            par ^= 1;
        }
    } else {
        // ---------------- consumers: prep (weights + xh), then select --------
        const int wblk = blockIdx.x - NB;        // 0..247
        // prep in the spin shadow (workers would idle until first publish)
        {
            const int wtid = wblk * 512 + tid;   // 0..126975
            const int NW = 248 * 512;
#pragma unroll 1
            for (int m = 0; m < 9; ++m) {
                const int kp = pa.kp[m], kr = pa.kr[m], nc = pa.nc[m];
                const float* src = pa.src[m];
                _Float16* dst = pa.dst[m];
                const int tot = kp * nc;
                for (int i = wtid; i < tot; i += NW) {
                    int n = i / kp, k = i - n * kp;
                    dst[i] = (k < kr) ? (_Float16)src[(size_t)k * nc + n]
                                      : (_Float16)0.f;
                }
            }
            if (xh) {   // f16 copy of x: halves mlp gather bytes, drops cvt
                const float4* xs = (const float4*)x;
                f16x4* xd = (f16x4*)xh;
                const int tot = NB * NP * 64 / 4;   // 524288 float4s
                for (int i = wtid; i < tot; i += NW) {
                    float4 v = xs[i];
                    f16x4 h = {(_Float16)v.x, (_Float16)v.y,
                               (_Float16)v.z, (_Float16)v.w};
                    xd[i] = h;
                }
            }
        }
        const int wid = tid >> 6;                // 0..7
        const int wave_id = wblk * 8 + wid;      // 0..1983
        const int NWAVE = 248 * 8;               // 1984
        const int NTASK = 3 * NB * NS;           // 24576
        for (int T = wave_id; T < NTASK; T += NWAVE) {
            const int s = T / 24;                // center index, ascending
            const int r = T - s * 24;
            const int b = r & 7;
            const int seg = r >> 3;
            const int scid = b * NS + s;
            while (__hip_atomic_load(&prog[b * PROGSTRIDE], __ATOMIC_ACQUIRE,
                                     __HIP_MEMORY_SCOPE_AGENT) <= (unsigned)s)
                __builtin_amdgcn_s_sleep(32);
            const float* pb = pos + (size_t)b * NP * 3;
            if (seg == 0)
                select_center<16>(pb, centers, nbr0, nval,
                                  (float)(0.1 * 0.1), scid);
            else if (seg == 1)
                select_center<32>(pb, centers, nbr1, nval + 8192,
                                  (float)(0.2 * 0.2), scid);
            else
                select_center<64>(pb, centers, nbr2, nval + 16384,
                                  (float)(0.4 * 0.4), scid);
        }
    }
}

// =========================== MFMA MLP ==============================
// ROUND-15: T2-style XOR swizzle on h1/h2 (counter evidence: R14 profiled
// mlp_all at SQ_LDS_BANK_CONFLICT = 1.0e7; fps = 0). Rows stride S2/S3 =
// 136 hw = 68 dwords; 68%32 = 4 -> ds_read_b128 lanes with equal (lm+lq)%8
// share one 4-bank span = 8-way conflict class. 16B row alignment for
// f16x8 forbids fixing via padding (any legal pad keeps stride%32 multiple
// of 4). Fix: col_hw ^= (row&7)<<3 (byte ^ (row&7)<<4) on BOTH the f16
// writes and the 16B reads of h1/h2 — permutes whole 16B blocks within the
// row (mask <= 112 B < data span; alignment preserved) -> read start banks
// become 4*((lm + (lq^(lm&7)))%8): exactly 2 lanes/start = free (m136).
// Pure address permutation -> bit-identical. feat (stride%32=20, 2-way
// already) stays unswizzled.
// Keeps: R14 staged-nbr + xh gather, R13 single-buf 3 blk/CU, R12 CPB
// M-batch, R11 cloud->XCD remap.
template <int KN, int CPB, int C1, int C2, int C3, int OFF, int NCTR>
__device__ void mlp_body(
        char* smem,
        const float* __restrict__ x, const _Float16* __restrict__ xh,
        const float* __restrict__ pos,
        const float* __restrict__ centers,
        const int* __restrict__ nbr, const int* __restrict__ nvalid,
        const _Float16* __restrict__ wt1, const _Float16* __restrict__ wt2,
        const _Float16* __restrict__ wt3,
        const float* __restrict__ b1, const float* __restrict__ b2,
        const float* __restrict__ b3,
        float* __restrict__ out, int blk) {
    constexpr int M = KN * CPB;             // batched tile rows (64 everywhere)
    constexpr int K1P = 96;                 // 67 padded to 96
    constexpr int S1 = K1P + 8;             // 104 elems = 208 B
    constexpr int S2 = C1 + 8;
    constexpr int S3 = C2 + 8;
    constexpr int MT = M / 16;
    constexpr int NCH1 = C1 / 4, NCH2 = C2 / 4, NCH3 = C3 / 4;
    constexpr int NT1 = NCH1 / 16, NT2 = NCH2 / 16, NT3 = NCH3 / 16;
    constexpr int KT1 = K1P / 32, KT2 = C1 / 32, KT3 = C2 / 32;
    constexpr int NBATCH = NCTR / CPB;

    _Float16* feat = (_Float16*)smem;            // M*S1, 16B-aligned
    _Float16* h1 = feat + M * S1;
    _Float16* h2 = h1 + M * S2;
    int* outmax = (int*)(h2 + M * S3);           // CPB * C3 ints
    int* nbuf = outmax + CPB * C3;               // M ints (staged nbr)
    int* nvbuf = nbuf + M;                       // CPB ints (staged nvalid)

    const int tid = threadIdx.x;
    const int lane = tid & 63;
    const int w = tid >> 6;
    const int lm = lane & 15;
    const int lq = lane >> 4;

    // ---- resident weight fragments + biases (per wave N-chunk) ----
    f16x8 wf1[NT1][KT1], wf2[NT2][KT2], wf3[NT3][KT3];
    float bb1[NT1], bb2[NT2], bb3[NT3];
#pragma unroll
    for (int nt = 0; nt < NT1; ++nt) {
        int n = w * NCH1 + nt * 16 + lm;
        bb1[nt] = b1[n];
#pragma unroll
        for (int kt = 0; kt < KT1; ++kt)
            wf1[nt][kt] = *(const f16x8*)(wt1 + (size_t)n * K1P + kt * 32 + lq * 8);
    }
#pragma unroll
    for (int nt = 0; nt < NT2; ++nt) {
        int n = w * NCH2 + nt * 16 + lm;
        bb2[nt] = b2[n];
#pragma unroll
        for (int kt = 0; kt < KT2; ++kt)
            wf2[nt][kt] = *(const f16x8*)(wt2 + (size_t)n * C1 + kt * 32 + lq * 8);
    }
#pragma unroll
    for (int nt = 0; nt < NT3; ++nt) {
        int n = w * NCH3 + nt * 16 + lm;
        bb3[nt] = b3[n];
#pragma unroll
        for (int kt = 0; kt < KT3; ++kt)
            wf3[nt][kt] = *(const f16x8*)(wt3 + (size_t)n * C2 + kt * 32 + lq * 8);
    }

    for (int bt = 0; bt < NBATCH; ++bt) {
        const int cid0 = blk * NCTR + bt * CPB;
        __syncthreads();   // gate: prev out-write done; LDS reusable

        for (int i = tid; i < CPB * C3; i += 256) outmax[i] = 0;
        // stage indices: removes the per-row dependent nbr load from gather
        for (int i = tid; i < M; i += 256) {
            const int c = i / KN;
            nbuf[i] = nbr[(size_t)(cid0 + c) * KN + (i - c * KN)];
        }
        if (tid < CPB) nvbuf[tid] = nvalid[cid0 + tid];
        __syncthreads();   // nbuf/nvbuf visible

        // ---- gather batch of CPB centers: row r -> center r/KN, local row
        // r%KN; stale rows row-local through MFMA, relu(NaN)=0, masked at L3.
        if (xh) {
            for (int it = tid; it < M * 8; it += 256) {
                const int r = it >> 3, sub = it & 7;
                const int c = r / KN, lr = r - c * KN;
                if (lr < nvbuf[c]) {
                    int pt = nbuf[r];
                    f16x8 hv = *(const f16x8*)(
                        xh + ((size_t)((((cid0 + c) >> 10)) * NP) + pt) * 64 + sub * 8);
                    *(f16x8*)(feat + r * S1 + sub * 8) = hv;
                }
            }
        } else {
            for (int it = tid; it < M * 16; it += 256) {
                const int r = it >> 4, sub = it & 15;
                const int c = r / KN, lr = r - c * KN;
                if (lr < nvbuf[c]) {
                    int pt = nbuf[r];
                    float4 v = *(const float4*)(
                        x + ((size_t)((((cid0 + c) >> 10)) * NP) + pt) * 64 + sub * 4);
                    f16x4 hv = {(_Float16)v.x, (_Float16)v.y, (_Float16)v.z, (_Float16)v.w};
                    *(f16x4*)(feat + r * S1 + sub * 4) = hv;
                }
            }
        }
        for (int it = tid; it < M * 4; it += 256) {
            const int r = it >> 2, q = it & 3;
            const int c = r / KN, lr = r - c * KN;
            const int cid = cid0 + c;
            f16x8 z = {(_Float16)0.f, (_Float16)0.f, (_Float16)0.f, (_Float16)0.f,
                       (_Float16)0.f, (_Float16)0.f, (_Float16)0.f, (_Float16)0.f};
            if (q == 0 && lr < nvbuf[c]) {
                int pt = nbuf[r];
                const float* pr = pos + ((size_t)((cid >> 10) * NP) + pt) * 3;
                z[0] = (_Float16)(pr[0] - centers[cid * 3 + 0]);
                z[1] = (_Float16)(pr[1] - centers[cid * 3 + 1]);
                z[2] = (_Float16)(pr[2] - centers[cid * 3 + 2]);
            }
            *(f16x8*)(feat + r * S1 + 64 + q * 8) = z;
        }
        __syncthreads();

        // ---- layer 1: feat[M x 96] -> h1[M x C1] (swizzled write) ----
#pragma unroll
        for (int mt = 0; mt < MT; ++mt) {
            f16x8 a[KT1];
#pragma unroll
            for (int kt = 0; kt < KT1; ++kt)
                a[kt] = *(const f16x8*)(feat + (mt * 16 + lm) * S1 + kt * 32 + lq * 8);
#pragma unroll
            for (int nt = 0; nt < NT1; ++nt) {
                f32x4 acc = {bb1[nt], bb1[nt], bb1[nt], bb1[nt]};
#pragma unroll
                for (int kt = 0; kt < KT1; ++kt)
                    acc = __builtin_amdgcn_mfma_f32_16x16x32_f16(a[kt], wf1[nt][kt], acc, 0, 0, 0);
                const int gc = w * NCH1 + nt * 16 + lm;
#pragma unroll
                for (int rg = 0; rg < 4; ++rg) {
                    const int row = mt * 16 + lq * 4 + rg;
                    h1[row * S2 + (gc ^ ((row & 7) << 3))] =
                        (_Float16)fmaxf(acc[rg], 0.f);
                }
            }
        }
        __syncthreads();

        // ---- layer 2: h1[M x C1] -> h2[M x C2] (swizzled read + write) ----
#pragma unroll
        for (int mt = 0; mt < MT; ++mt) {
            f16x8 a[KT2];
#pragma unroll
            for (int kt = 0; kt < KT2; ++kt)
                a[kt] = *(const f16x8*)(h1 + (mt * 16 + lm) * S2 +
                                        ((kt * 32 + lq * 8) ^ ((lm & 7) << 3)));
#pragma unroll
            for (int nt = 0; nt < NT2; ++nt) {
                f32x4 acc = {bb2[nt], bb2[nt], bb2[nt], bb2[nt]};
#pragma unroll
                for (int kt = 0; kt < KT2; ++kt)
                    acc = __builtin_amdgcn_mfma_f32_16x16x32_f16(a[kt], wf2[nt][kt], acc, 0, 0, 0);
                const int gc = w * NCH2 + nt * 16 + lm;
#pragma unroll
                for (int rg = 0; rg < 4; ++rg) {
                    const int row = mt * 16 + lq * 4 + rg;
                    h2[row * S3 + (gc ^ ((row & 7) << 3))] =
                        (_Float16)fmaxf(acc[rg], 0.f);
                }
            }
        }
        __syncthreads();

        // ---- layer 3 + masked max (swizzled read; tile mt -> center) ----
#pragma unroll
        for (int mt = 0; mt < MT; ++mt) {
            constexpr int TPC = KN / 16;       // tiles per center
            const int c = mt / TPC;            // batch-local center of tile mt
            const int nv = nvbuf[c];
            const int lr0 = (mt % TPC) * 16;   // tile's first local row
            f16x8 a[KT3];
#pragma unroll
            for (int kt = 0; kt < KT3; ++kt)
                a[kt] = *(const f16x8*)(h2 + (mt * 16 + lm) * S3 +
                                        ((kt * 32 + lq * 8) ^ ((lm & 7) << 3)));
#pragma unroll
            for (int nt = 0; nt < NT3; ++nt) {
                f32x4 acc = {bb3[nt], bb3[nt], bb3[nt], bb3[nt]};
#pragma unroll
                for (int kt = 0; kt < KT3; ++kt)
                    acc = __builtin_amdgcn_mfma_f32_16x16x32_f16(a[kt], wf3[nt][kt], acc, 0, 0, 0);
                float mx = -1.f;
#pragma unroll
                for (int rg = 0; rg < 4; ++rg) {
                    int lr = lr0 + lq * 4 + rg;
                    float v = fmaxf(acc[rg], 0.f);
                    if (lr < nv) mx = fmaxf(mx, v);
                }
                mx = fmaxf(mx, __shfl_xor(mx, 16));
                mx = fmaxf(mx, __shfl_xor(mx, 32));
                if (lane < 16)
                    atomicMax(&outmax[c * C3 + w * NCH3 + nt * 16 + lm],
                              __float_as_int(mx));
            }
        }
        __syncthreads();
        for (int i = tid; i < CPB * C3; i += 256) {
            const int c = i / C3, j = i - c * C3;
            out[(size_t)(cid0 + c) * 640 + OFF + j] = __int_as_float(outmax[i]);
        }
        // next iteration's gate barrier orders this against outmax re-zero
    }
}

struct MlpW {
    const _Float16* w[9];
    const float* bias[9];
};

// cloud->XCD affinity remap (R11, measured −15us): cloud = sblk&7,
// octet = sblk>>3 -> each XCD works one cloud per segment phase.
__global__ __launch_bounds__(256, 2) void mlp_all(
        const float* __restrict__ x, const _Float16* __restrict__ xh,
        const float* __restrict__ pos,
        const float* __restrict__ centers,
        const int* __restrict__ nbr0, const int* __restrict__ nbr1,
        const int* __restrict__ nbr2, const int* __restrict__ nval,
        MlpW ww, float* __restrict__ out) {
    extern __shared__ char smem[];
    const int blk = blockIdx.x;
    const int sblk = blk & 1023;
    const int eblk = (sblk & 7) * 128 + (sblk >> 3);   // cloud*128 + octet
    if (blk < 1024)
        mlp_body<16, 4, 64, 64, 128, 0, 8>(smem, x, xh, pos, centers, nbr0, nval,
            ww.w[0], ww.w[1], ww.w[2], ww.bias[0], ww.bias[1], ww.bias[2], out, eblk);
    else if (blk < 2048)
        mlp_body<32, 2, 128, 128, 256, 128, 8>(smem, x, xh, pos, centers, nbr1, nval + 8192,
            ww.w[3], ww.w[4], ww.w[5], ww.bias[3], ww.bias[4], ww.bias[5], out, eblk);
    else
        mlp_body<64, 1, 128, 128, 256, 384, 8>(smem, x, xh, pos, centers, nbr2, nval + 16384,
            ww.w[6], ww.w[7], ww.w[8], ww.bias[6], ww.bias[7], ww.bias[8], out, eblk);
}

// ========================= launcher ===========================
extern "C" void kernel_launch(void* const* d_in, const int* in_sizes, int n_in,
                              void* d_out, int out_size, void* d_ws, size_t ws_size,
                              hipStream_t stream) {
    const float* x = (const float*)d_in[0];
    const float* pos = (const float*)d_in[1];
    const float* W0_0 = (const float*)d_in[3];
    const float* b0_0 = (const float*)d_in[4];
    const float* W0_1 = (const float*)d_in[5];
    const float* b0_1 = (const float*)d_in[6];
    const float* W0_2 = (const float*)d_in[7];
    const float* b0_2 = (const float*)d_in[8];
    const float* W1_0 = (const float*)d_in[9];
    const float* b1_0 = (const float*)d_in[10];
    const float* W1_1 = (const float*)d_in[11];
    const float* b1_1 = (const float*)d_in[12];
    const float* W1_2 = (const float*)d_in[13];
    const float* b1_2 = (const float*)d_in[14];
    const float* W2_0 = (const float*)d_in[15];
    const float* b2_0 = (const float*)d_in[16];
    const float* W2_1 = (const float*)d_in[17];
    const float* b2_1 = (const float*)d_in[18];
    const float* W2_2 = (const float*)d_in[19];
    const float* b2_2 = (const float*)d_in[20];

    float* out = (float*)d_out;
    char* ws = (char*)d_ws;
    float* centers = (float*)(ws + 0);                 //  98304 B
    int* nbr0 = (int*)(ws + 98304);                    //  524288 B
    int* nbr1 = (int*)(ws + 622592);                   //  1048576 B
    int* nbr2 = (int*)(ws + 1671168);                  //  2097152 B
    int* nval = (int*)(ws + 3768320);                  //  98304 B
    // f16 transposed weights
    _Float16* w0t1 = (_Float16*)(ws + 3866624);        //  64*96  = 12288 B
    _Float16* w0t2 = (_Float16*)(ws + 3878912);        //  64*64  =  8192 B
    _Float16* w0t3 = (_Float16*)(ws + 3887104);        // 128*64  = 16384 B
    _Float16* w1t1 = (_Float16*)(ws + 3903488);        // 128*96  = 24576 B
    _Float16* w1t2 = (_Float16*)(ws + 3928064);        // 128*128 = 32768 B
    _Float16* w1t3 = (_Float16*)(ws + 3960832);        // 256*128 = 65536 B
    _Float16* w2t1 = (_Float16*)(ws + 4026368);
    _Float16* w2t2 = (_Float16*)(ws + 4050944);
    _Float16* w2t3 = (_Float16*)(ws + 4083712);        // end 4149248 B
    unsigned* prog = (unsigned*)(ws + 4149248);        // 8 x 128B progress lines
    // optional f16 copy of x (halves mlp gather traffic) — only if ws allows
    _Float16* xh = (ws_size >= (size_t)XH_OFF + XH_BYTES)
                       ? (_Float16*)(ws + XH_OFF) : (_Float16*)0;

    float* out_pos = out + (size_t)8192 * 640;
    float* out_batch = out_pos + (size_t)8192 * 3;

    hipMemsetAsync(prog, 0, NB * PROGSTRIDE * sizeof(unsigned), stream);

    PrepArgs pa;
    pa.src[0] = W0_0; pa.dst[0] = w0t1; pa.kr[0] = 67;  pa.kp[0] = 96;  pa.nc[0] = 64;
    pa.src[1] = W0_1; pa.dst[1] = w0t2; pa.kr[1] = 64;  pa.kp[1] = 64;  pa.nc[1] = 64;
    pa.src[2] = W0_2; pa.dst[2] = w0t3; pa.kr[2] = 64;  pa.kp[2] = 64;  pa.nc[2] = 128;
    pa.src[3] = W1_0; pa.dst[3] = w1t1; pa.kr[3] = 67;  pa.kp[3] = 96;  pa.nc[3] = 128;
    pa.src[4] = W1_1; pa.dst[4] = w1t2; pa.kr[4] = 128; pa.kp[4] = 128; pa.nc[4] = 128;
    pa.src[5] = W1_2; pa.dst[5] = w1t3; pa.kr[5] = 128; pa.kp[5] = 128; pa.nc[5] = 256;
    pa.src[6] = W2_0; pa.dst[6] = w2t1; pa.kr[6] = 67;  pa.kp[6] = 96;  pa.nc[6] = 128;
    pa.src[7] = W2_1; pa.dst[7] = w2t2; pa.kr[7] = 128; pa.kp[7] = 128; pa.nc[7] = 128;
    pa.src[8] = W2_2; pa.dst[8] = w2t3; pa.kr[8] = 128; pa.kp[8] = 128; pa.nc[8] = 256;

    fps_select_fused<<<dim3(256), dim3(512), 0, stream>>>(
        pos, centers, out_pos, out_batch, nbr0, nbr1, nbr2, nval, prog, pa,
        x, xh);

    MlpW ww;
    ww.w[0] = w0t1; ww.w[1] = w0t2; ww.w[2] = w0t3;
    ww.w[3] = w1t1; ww.w[4] = w1t2; ww.w[5] = w1t3;
    ww.w[6] = w2t1; ww.w[7] = w2t2; ww.w[8] = w2t3;
    ww.bias[0] = b0_0; ww.bias[1] = b0_1; ww.bias[2] = b0_2;
    ww.bias[3] = b1_0; ww.bias[4] = b1_1; ww.bias[5] = b1_2;
    ww.bias[6] = b2_0; ww.bias[7] = b2_1; ww.bias[8] = b2_2;

    // dynamic LDS unchanged (50448 x 3 blocks/CU = 151344 <= 163840/CU)
    mlp_all<<<dim3(3072), dim3(256), 50448, stream>>>(
        x, xh, pos, centers, nbr0, nbr1, nbr2, nval, ww, out);
}

// Round 16
// 1069.358 us; speedup vs baseline: 1.0247x; 1.0247x over previous
//
#include <hip/hip_runtime.h>

#define NB 8
#define NP 4096
#define NS 1024
#define PROGSTRIDE 32   // one 128B cache line per cloud's progress word
#define XH_OFF 4150272          // f16 copy of x (4 MB), if ws_size allows
#define XH_BYTES (NB * NP * 64 * 2)

typedef _Float16 f16x8 __attribute__((ext_vector_type(8)));
typedef _Float16 f16x4 __attribute__((ext_vector_type(4)));
typedef float f32x4 __attribute__((ext_vector_type(4)));

// DPP-fused max step: v = max(v, dpp_move(v, ctrl)). bound_ctrl=false keeps
// old value on invalid lanes -> max(v,v)=v, harmless.
#define DPP_MAX(v, ctrl)                                                     \
    v = fmaxf(v, __int_as_float(__builtin_amdgcn_update_dpp(                 \
                __float_as_int(v), __float_as_int(v), (ctrl), 0xf, 0xf, false)))

struct PrepArgs {
    const float* src[9];
    _Float16* dst[9];
    int kr[9], kp[9], nc[9];
};

// ========================= Selection body ==========================
// Early-exit binary search on uint(d2) bits, no LDS staging, one center per
// wave. Bit-identical to exact top-k (tie path kept as fallback). FROZEN.
template <int K>
__device__ __forceinline__ void select_center(
        const float* __restrict__ pb,
        const float* __restrict__ centers,
        int* __restrict__ nbr, int* __restrict__ nvalid,
        float r2, int scid) {
#pragma clang fp contract(off)
    const int lane = threadIdx.x & 63;
    const unsigned kr2 = __float_as_uint(r2);
    const float cx = centers[scid * 3 + 0];
    const float cy = centers[scid * 3 + 1];
    const float cz = centers[scid * 3 + 2];

    unsigned key[64];
#pragma unroll
    for (int i = 0; i < 64; ++i) {
        const float* pp = pb + (size_t)(lane + i * 64) * 3;
        float dx = pp[0] - cx; float sx = dx * dx;
        float dy = pp[1] - cy; float sy = dy * dy;
        float dz = pp[2] - cz; float sz = dz * dz;
        float d2 = sx + sy; d2 = d2 + sz;
        key[i] = __float_as_uint(d2);
    }

    const unsigned long long below = (1ull << lane) - 1ull;
    int c_cnt = 0;
#pragma unroll
    for (int i = 0; i < 64; ++i)
        c_cnt += __popcll(__ballot(key[i] <= kr2));

    unsigned thr = kr2;          // threshold for the no-ties write pass
    int nv = c_cnt;
    bool need_ties = false;
    unsigned tkey = 0;
    if (c_cnt > K) {
        nv = K;
        unsigned lo = 0, hi = kr2;
        need_ties = true;
        while (lo < hi) {
            unsigned mid = lo + ((hi - lo) >> 1);
            int cnt = 0;
#pragma unroll
            for (int i = 0; i < 64; ++i)
                cnt += __popcll(__ballot(key[i] <= mid));
            if (cnt == K) { thr = mid; need_ties = false; break; }
            if (cnt > K) hi = mid; else lo = mid + 1;
        }
        tkey = lo;               // only meaningful if need_ties
    }

    if (!need_ties) {
        int base = 0;
#pragma unroll
        for (int i = 0; i < 64; ++i) {
            unsigned long long m = __ballot(key[i] <= thr);
            if (key[i] <= thr)
                nbr[(size_t)scid * K + base + __popcll(m & below)] = lane + i * 64;
            base += __popcll(m);
        }
    } else {
        const unsigned t = tkey;
        int m_cnt = 0;
#pragma unroll
        for (int i = 0; i < 64; ++i)
            m_cnt += __popcll(__ballot(key[i] < t));
        const int rem = K - m_cnt;
        int base = 0, tcnt = 0;
#pragma unroll
        for (int i = 0; i < 64; ++i) {
            unsigned long long lt = __ballot(key[i] < t);
            unsigned long long eq = __ballot(key[i] == t);
            if (key[i] < t) {
                nbr[(size_t)scid * K + base + __popcll(lt & below)] = lane + i * 64;
            } else if (key[i] == t) {
                int tr = tcnt + __popcll(eq & below);
                if (tr < rem) nbr[(size_t)scid * K + (m_cnt + tr)] = lane + i * 64;
            }
            base += __popcll(lt);
            tcnt += __popcll(eq);
        }
    }
    if (lane == 0) nvalid[scid] = nv;
}

// ================== FUSED FPS (producers) + SELECT (consumers) ==============
// MEASURED-GOOD (fused dispatch ~797-804us, six-times-stable). fps 8 blocks
// + 248 select worker blocks (1984 waves), prep (weights + xh) in worker
// preamble (spin shadow), padded prog lines, s_sleep(32), cadence-16
// publish. FROZEN — R3 (LDS cbuf), R5 (spin contention), R7/R9 (triple
// fusion) all measured neutral or worse.
// NOTE: fp contract(off) is REQUIRED — contraction perturbs d2 ulps and can
// flip FPS argmax near-ties -> different centers -> output blowup.
__global__ __launch_bounds__(512, 1) void fps_select_fused(
        const float* __restrict__ pos,
        float* __restrict__ centers,
        float* __restrict__ out_pos,
        float* __restrict__ out_batch,
        int* __restrict__ nbr0, int* __restrict__ nbr1, int* __restrict__ nbr2,
        int* __restrict__ nval,
        unsigned* __restrict__ prog,
        PrepArgs pa,
        const float* __restrict__ x,
        _Float16* __restrict__ xh) {
#pragma clang fp contract(off)
    const int tid = threadIdx.x;
    const int lane = tid & 63;

    if (blockIdx.x < NB) {
        // ------------------------ producer: FPS ------------------------
        const int b = blockIdx.x;
        const int wid = tid >> 6;
        __shared__ float4 slot[2][8];   // [parity][wave]

        const float* pb = pos + (size_t)b * NP * 3;
        float px[8], py[8], pz[8], md[8];
        {
            const float4* pv = (const float4*)(pb + tid * 24);
            float4 q0 = pv[0], q1 = pv[1], q2 = pv[2];
            float4 q3 = pv[3], q4 = pv[4], q5 = pv[5];
            px[0] = q0.x; py[0] = q0.y; pz[0] = q0.z;
            px[1] = q0.w; py[1] = q1.x; pz[1] = q1.y;
            px[2] = q1.z; py[2] = q1.w; pz[2] = q2.x;
            px[3] = q2.y; py[3] = q2.z; pz[3] = q2.w;
            px[4] = q3.x; py[4] = q3.y; pz[4] = q3.z;
            px[5] = q3.w; py[5] = q4.x; pz[5] = q4.y;
            px[6] = q4.z; py[6] = q4.w; pz[6] = q5.x;
            px[7] = q5.y; py[7] = q5.z; pz[7] = q5.w;
        }
#pragma unroll
        for (int j = 0; j < 8; ++j) md[j] = __builtin_inff();
        for (int t = tid; t < NS; t += 512) out_batch[b * NS + t] = (float)b;

        float cx = pb[0], cy = pb[1], cz = pb[2];
        if (tid == 0) {
            size_t o = (size_t)(b * NS) * 3;
            centers[o + 0] = cx; centers[o + 1] = cy; centers[o + 2] = cz;
            out_pos[o + 0] = cx; out_pos[o + 1] = cy; out_pos[o + 2] = cz;
        }

        int par = 0;
        for (int t = 1; t < NS; ++t) {
            float bv = -1.0f, bx = cx, by = cy, bz = cz;
#pragma unroll
            for (int j = 0; j < 8; ++j) {
                float dx = px[j] - cx; float sx = dx * dx;
                float dy = py[j] - cy; float sy = dy * dy;
                float dz = pz[j] - cz; float sz = dz * dz;
                float d = sx + sy; d = d + sz;
                float m = fminf(md[j], d);
                md[j] = m;
                bool c = m > bv;                 // strict >: first j wins ties
                bv = c ? m : bv;
                bx = c ? px[j] : bx;
                by = c ? py[j] : by;
                bz = c ? pz[j] : bz;
            }
            // wave max via DPP (result valid in lane 63), then SGPR broadcast
            float v = bv;
            DPP_MAX(v, 0x111);   // row_shr:1
            DPP_MAX(v, 0x112);   // row_shr:2
            DPP_MAX(v, 0x114);   // row_shr:4
            DPP_MAX(v, 0x118);   // row_shr:8
            DPP_MAX(v, 0x142);   // row_bcast:15
            DPP_MAX(v, 0x143);   // row_bcast:31
            const float mx = __int_as_float(
                __builtin_amdgcn_readlane(__float_as_int(v), 63));
            unsigned long long tie = __ballot(bv == mx);
            if (lane == __ffsll(tie) - 1)        // lowest lane among ties
                slot[par][wid] = make_float4(mx, bx, by, bz);
            __syncthreads();
            float4 s0 = slot[par][0], s1 = slot[par][1];
            float4 s2 = slot[par][2], s3 = slot[par][3];
            float4 s4 = slot[par][4], s5 = slot[par][5];
            float4 s6 = slot[par][6], s7 = slot[par][7];
            float4 a01 = (s1.x > s0.x) ? s1 : s0;   // ties keep lower wave
            float4 a23 = (s3.x > s2.x) ? s3 : s2;
            float4 a45 = (s5.x > s4.x) ? s5 : s4;
            float4 a67 = (s7.x > s6.x) ? s7 : s6;
            float4 b03 = (a23.x > a01.x) ? a23 : a01;
            float4 b47 = (a67.x > a45.x) ? a67 : a45;
            float4 wn = (b47.x > b03.x) ? b47 : b03;
            cx = wn.y; cy = wn.z; cz = wn.w;
            if (tid == 0) {
                size_t o = (size_t)(b * NS + t) * 3;
                centers[o + 0] = cx; centers[o + 1] = cy; centers[o + 2] = cz;
                out_pos[o + 0] = cx; out_pos[o + 1] = cy; out_pos[o + 2] = cz;
                if ((t & 15) == 15)   // cadence-16 publish; t=1023 -> 1024
                    __hip_atomic_store(&prog[b * PROGSTRIDE], (unsigned)(t + 1),
                                       __ATOMIC_RELEASE, __HIP_MEMORY_SCOPE_AGENT);
            }
            par ^= 1;
        }
    } else {
        // ---------------- consumers: prep (weights + xh), then select --------
        const int wblk = blockIdx.x - NB;        // 0..247
        // prep in the spin shadow (workers would idle until first publish)
        {
            const int wtid = wblk * 512 + tid;   // 0..126975
            const int NW = 248 * 512;
#pragma unroll 1
            for (int m = 0; m < 9; ++m) {
                const int kp = pa.kp[m], kr = pa.kr[m], nc = pa.nc[m];
                const float* src = pa.src[m];
                _Float16* dst = pa.dst[m];
                const int tot = kp * nc;
                for (int i = wtid; i < tot; i += NW) {
                    int n = i / kp, k = i - n * kp;
                    dst[i] = (k < kr) ? (_Float16)src[(size_t)k * nc + n]
                                      : (_Float16)0.f;
                }
            }
            if (xh) {   // f16 copy of x: halves mlp gather bytes, drops cvt
                const float4* xs = (const float4*)x;
                f16x4* xd = (f16x4*)xh;
                const int tot = NB * NP * 64 / 4;   // 524288 float4s
                for (int i = wtid; i < tot; i += NW) {
                    float4 v = xs[i];
                    f16x4 h = {(_Float16)v.x, (_Float16)v.y,
                               (_Float16)v.z, (_Float16)v.w};
                    xd[i] = h;
                }
            }
        }
        const int wid = tid >> 6;                // 0..7
        const int wave_id = wblk * 8 + wid;      // 0..1983
        const int NWAVE = 248 * 8;               // 1984
        const int NTASK = 3 * NB * NS;           // 24576
        for (int T = wave_id; T < NTASK; T += NWAVE) {
            const int s = T / 24;                // center index, ascending
            const int r = T - s * 24;
            const int b = r & 7;
            const int seg = r >> 3;
            const int scid = b * NS + s;
            while (__hip_atomic_load(&prog[b * PROGSTRIDE], __ATOMIC_ACQUIRE,
                                     __HIP_MEMORY_SCOPE_AGENT) <= (unsigned)s)
                __builtin_amdgcn_s_sleep(32);
            const float* pb = pos + (size_t)b * NP * 3;
            if (seg == 0)
                select_center<16>(pb, centers, nbr0, nval,
                                  (float)(0.1 * 0.1), scid);
            else if (seg == 1)
                select_center<32>(pb, centers, nbr1, nval + 8192,
                                  (float)(0.2 * 0.2), scid);
            else
                select_center<64>(pb, centers, nbr2, nval + 16384,
                                  (float)(0.4 * 0.4), scid);
        }
    }
}

// =========================== MFMA MLP ==============================
// ROUND-16 = R14 VERBATIM (measured best, 1071.0us). R15's h1/h2 XOR
// swizzle REGRESSED (+25us): the 1.0e7 bank-conflict cycles were already
// hidden under cross-block TLP, while the per-access XOR address VALU work
// was NOT hideable (issue-port bound). Lesson: with >=3 blocks/CU of
// independent work, only issue-count reductions move this kernel;
// latency-class counter "fixes" that add instructions are net-negative.
// Keeps: R14 staged-nbr + xh gather, R13 single-buf 3 blk/CU, R12 CPB
// M-batch, R11 cloud->XCD remap.
template <int KN, int CPB, int C1, int C2, int C3, int OFF, int NCTR>
__device__ void mlp_body(
        char* smem,
        const float* __restrict__ x, const _Float16* __restrict__ xh,
        const float* __restrict__ pos,
        const float* __restrict__ centers,
        const int* __restrict__ nbr, const int* __restrict__ nvalid,
        const _Float16* __restrict__ wt1, const _Float16* __restrict__ wt2,
        const _Float16* __restrict__ wt3,
        const float* __restrict__ b1, const float* __restrict__ b2,
        const float* __restrict__ b3,
        float* __restrict__ out, int blk) {
    constexpr int M = KN * CPB;             // batched tile rows (64 everywhere)
    constexpr int K1P = 96;                 // 67 padded to 96
    constexpr int S1 = K1P + 8;             // 104 elems = 208 B
    constexpr int S2 = C1 + 8;
    constexpr int S3 = C2 + 8;
    constexpr int MT = M / 16;
    constexpr int NCH1 = C1 / 4, NCH2 = C2 / 4, NCH3 = C3 / 4;
    constexpr int NT1 = NCH1 / 16, NT2 = NCH2 / 16, NT3 = NCH3 / 16;
    constexpr int KT1 = K1P / 32, KT2 = C1 / 32, KT3 = C2 / 32;
    constexpr int NBATCH = NCTR / CPB;

    _Float16* feat = (_Float16*)smem;            // M*S1, 16B-aligned
    _Float16* h1 = feat + M * S1;
    _Float16* h2 = h1 + M * S2;
    int* outmax = (int*)(h2 + M * S3);           // CPB * C3 ints
    int* nbuf = outmax + CPB * C3;               // M ints (staged nbr)
    int* nvbuf = nbuf + M;                       // CPB ints (staged nvalid)

    const int tid = threadIdx.x;
    const int lane = tid & 63;
    const int w = tid >> 6;
    const int lm = lane & 15;
    const int lq = lane >> 4;

    // ---- resident weight fragments + biases (per wave N-chunk) ----
    f16x8 wf1[NT1][KT1], wf2[NT2][KT2], wf3[NT3][KT3];
    float bb1[NT1], bb2[NT2], bb3[NT3];
#pragma unroll
    for (int nt = 0; nt < NT1; ++nt) {
        int n = w * NCH1 + nt * 16 + lm;
        bb1[nt] = b1[n];
#pragma unroll
        for (int kt = 0; kt < KT1; ++kt)
            wf1[nt][kt] = *(const f16x8*)(wt1 + (size_t)n * K1P + kt * 32 + lq * 8);
    }
#pragma unroll
    for (int nt = 0; nt < NT2; ++nt) {
        int n = w * NCH2 + nt * 16 + lm;
        bb2[nt] = b2[n];
#pragma unroll
        for (int kt = 0; kt < KT2; ++kt)
            wf2[nt][kt] = *(const f16x8*)(wt2 + (size_t)n * C1 + kt * 32 + lq * 8);
    }
#pragma unroll
    for (int nt = 0; nt < NT3; ++nt) {
        int n = w * NCH3 + nt * 16 + lm;
        bb3[nt] = b3[n];
#pragma unroll
        for (int kt = 0; kt < KT3; ++kt)
            wf3[nt][kt] = *(const f16x8*)(wt3 + (size_t)n * C2 + kt * 32 + lq * 8);
    }

    for (int bt = 0; bt < NBATCH; ++bt) {
        const int cid0 = blk * NCTR + bt * CPB;
        __syncthreads();   // gate: prev out-write done; LDS reusable

        for (int i = tid; i < CPB * C3; i += 256) outmax[i] = 0;
        // stage indices: removes the per-row dependent nbr load from gather
        for (int i = tid; i < M; i += 256) {
            const int c = i / KN;
            nbuf[i] = nbr[(size_t)(cid0 + c) * KN + (i - c * KN)];
        }
        if (tid < CPB) nvbuf[tid] = nvalid[cid0 + tid];
        __syncthreads();   // nbuf/nvbuf visible

        // ---- gather batch of CPB centers: row r -> center r/KN, local row
        // r%KN; stale rows row-local through MFMA, relu(NaN)=0, masked at L3.
        if (xh) {
            for (int it = tid; it < M * 8; it += 256) {
                const int r = it >> 3, sub = it & 7;
                const int c = r / KN, lr = r - c * KN;
                if (lr < nvbuf[c]) {
                    int pt = nbuf[r];
                    f16x8 hv = *(const f16x8*)(
                        xh + ((size_t)((((cid0 + c) >> 10)) * NP) + pt) * 64 + sub * 8);
                    *(f16x8*)(feat + r * S1 + sub * 8) = hv;
                }
            }
        } else {
            for (int it = tid; it < M * 16; it += 256) {
                const int r = it >> 4, sub = it & 15;
                const int c = r / KN, lr = r - c * KN;
                if (lr < nvbuf[c]) {
                    int pt = nbuf[r];
                    float4 v = *(const float4*)(
                        x + ((size_t)((((cid0 + c) >> 10)) * NP) + pt) * 64 + sub * 4);
                    f16x4 hv = {(_Float16)v.x, (_Float16)v.y, (_Float16)v.z, (_Float16)v.w};
                    *(f16x4*)(feat + r * S1 + sub * 4) = hv;
                }
            }
        }
        for (int it = tid; it < M * 4; it += 256) {
            const int r = it >> 2, q = it & 3;
            const int c = r / KN, lr = r - c * KN;
            const int cid = cid0 + c;
            f16x8 z = {(_Float16)0.f, (_Float16)0.f, (_Float16)0.f, (_Float16)0.f,
                       (_Float16)0.f, (_Float16)0.f, (_Float16)0.f, (_Float16)0.f};
            if (q == 0 && lr < nvbuf[c]) {
                int pt = nbuf[r];
                const float* pr = pos + ((size_t)((cid >> 10) * NP) + pt) * 3;
                z[0] = (_Float16)(pr[0] - centers[cid * 3 + 0]);
                z[1] = (_Float16)(pr[1] - centers[cid * 3 + 1]);
                z[2] = (_Float16)(pr[2] - centers[cid * 3 + 2]);
            }
            *(f16x8*)(feat + r * S1 + 64 + q * 8) = z;
        }
        __syncthreads();

        // ---- layer 1: feat[M x 96] -> h1[M x C1] ----
#pragma unroll
        for (int mt = 0; mt < MT; ++mt) {
            f16x8 a[KT1];
#pragma unroll
            for (int kt = 0; kt < KT1; ++kt)
                a[kt] = *(const f16x8*)(feat + (mt * 16 + lm) * S1 + kt * 32 + lq * 8);
#pragma unroll
            for (int nt = 0; nt < NT1; ++nt) {
                f32x4 acc = {bb1[nt], bb1[nt], bb1[nt], bb1[nt]};
#pragma unroll
                for (int kt = 0; kt < KT1; ++kt)
                    acc = __builtin_amdgcn_mfma_f32_16x16x32_f16(a[kt], wf1[nt][kt], acc, 0, 0, 0);
                const int gc = w * NCH1 + nt * 16 + lm;
#pragma unroll
                for (int rg = 0; rg < 4; ++rg)
                    h1[(mt * 16 + lq * 4 + rg) * S2 + gc] = (_Float16)fmaxf(acc[rg], 0.f);
            }
        }
        __syncthreads();

        // ---- layer 2: h1[M x C1] -> h2[M x C2] ----
#pragma unroll
        for (int mt = 0; mt < MT; ++mt) {
            f16x8 a[KT2];
#pragma unroll
            for (int kt = 0; kt < KT2; ++kt)
                a[kt] = *(const f16x8*)(h1 + (mt * 16 + lm) * S2 + kt * 32 + lq * 8);
#pragma unroll
            for (int nt = 0; nt < NT2; ++nt) {
                f32x4 acc = {bb2[nt], bb2[nt], bb2[nt], bb2[nt]};
#pragma unroll
                for (int kt = 0; kt < KT2; ++kt)
                    acc = __builtin_amdgcn_mfma_f32_16x16x32_f16(a[kt], wf2[nt][kt], acc, 0, 0, 0);
                const int gc = w * NCH2 + nt * 16 + lm;
#pragma unroll
                for (int rg = 0; rg < 4; ++rg)
                    h2[(mt * 16 + lq * 4 + rg) * S3 + gc] = (_Float16)fmaxf(acc[rg], 0.f);
            }
        }
        __syncthreads();

        // ---- layer 3 + masked max (16-row tile mt -> center mt/(KN/16)) ----
#pragma unroll
        for (int mt = 0; mt < MT; ++mt) {
            constexpr int TPC = KN / 16;       // tiles per center
            const int c = mt / TPC;            // batch-local center of tile mt
            const int nv = nvbuf[c];
            const int lr0 = (mt % TPC) * 16;   // tile's first local row
            f16x8 a[KT3];
#pragma unroll
            for (int kt = 0; kt < KT3; ++kt)
                a[kt] = *(const f16x8*)(h2 + (mt * 16 + lm) * S3 + kt * 32 + lq * 8);
#pragma unroll
            for (int nt = 0; nt < NT3; ++nt) {
                f32x4 acc = {bb3[nt], bb3[nt], bb3[nt], bb3[nt]};
#pragma unroll
                for (int kt = 0; kt < KT3; ++kt)
                    acc = __builtin_amdgcn_mfma_f32_16x16x32_f16(a[kt], wf3[nt][kt], acc, 0, 0, 0);
                float mx = -1.f;
#pragma unroll
                for (int rg = 0; rg < 4; ++rg) {
                    int lr = lr0 + lq * 4 + rg;
                    float v = fmaxf(acc[rg], 0.f);
                    if (lr < nv) mx = fmaxf(mx, v);
                }
                mx = fmaxf(mx, __shfl_xor(mx, 16));
                mx = fmaxf(mx, __shfl_xor(mx, 32));
                if (lane < 16)
                    atomicMax(&outmax[c * C3 + w * NCH3 + nt * 16 + lm],
                              __float_as_int(mx));
            }
        }
        __syncthreads();
        for (int i = tid; i < CPB * C3; i += 256) {
            const int c = i / C3, j = i - c * C3;
            out[(size_t)(cid0 + c) * 640 + OFF + j] = __int_as_float(outmax[i]);
        }
        // next iteration's gate barrier orders this against outmax re-zero
    }
}

struct MlpW {
    const _Float16* w[9];
    const float* bias[9];
};

// cloud->XCD affinity remap (R11, measured −15us): cloud = sblk&7,
// octet = sblk>>3 -> each XCD works one cloud per segment phase.
__global__ __launch_bounds__(256, 2) void mlp_all(
        const float* __restrict__ x, const _Float16* __restrict__ xh,
        const float* __restrict__ pos,
        const float* __restrict__ centers,
        const int* __restrict__ nbr0, const int* __restrict__ nbr1,
        const int* __restrict__ nbr2, const int* __restrict__ nval,
        MlpW ww, float* __restrict__ out) {
    extern __shared__ char smem[];
    const int blk = blockIdx.x;
    const int sblk = blk & 1023;
    const int eblk = (sblk & 7) * 128 + (sblk >> 3);   // cloud*128 + octet
    if (blk < 1024)
        mlp_body<16, 4, 64, 64, 128, 0, 8>(smem, x, xh, pos, centers, nbr0, nval,
            ww.w[0], ww.w[1], ww.w[2], ww.bias[0], ww.bias[1], ww.bias[2], out, eblk);
    else if (blk < 2048)
        mlp_body<32, 2, 128, 128, 256, 128, 8>(smem, x, xh, pos, centers, nbr1, nval + 8192,
            ww.w[3], ww.w[4], ww.w[5], ww.bias[3], ww.bias[4], ww.bias[5], out, eblk);
    else
        mlp_body<64, 1, 128, 128, 256, 384, 8>(smem, x, xh, pos, centers, nbr2, nval + 16384,
            ww.w[6], ww.w[7], ww.w[8], ww.bias[6], ww.bias[7], ww.bias[8], out, eblk);
}

// ========================= launcher ===========================
extern "C" void kernel_launch(void* const* d_in, const int* in_sizes, int n_in,
                              void* d_out, int out_size, void* d_ws, size_t ws_size,
                              hipStream_t stream) {
    const float* x = (const float*)d_in[0];
    const float* pos = (const float*)d_in[1];
    const float* W0_0 = (const float*)d_in[3];
    const float* b0_0 = (const float*)d_in[4];
    const float* W0_1 = (const float*)d_in[5];
    const float* b0_1 = (const float*)d_in[6];
    const float* W0_2 = (const float*)d_in[7];
    const float* b0_2 = (const float*)d_in[8];
    const float* W1_0 = (const float*)d_in[9];
    const float* b1_0 = (const float*)d_in[10];
    const float* W1_1 = (const float*)d_in[11];
    const float* b1_1 = (const float*)d_in[12];
    const float* W1_2 = (const float*)d_in[13];
    const float* b1_2 = (const float*)d_in[14];
    const float* W2_0 = (const float*)d_in[15];
    const float* b2_0 = (const float*)d_in[16];
    const float* W2_1 = (const float*)d_in[17];
    const float* b2_1 = (const float*)d_in[18];
    const float* W2_2 = (const float*)d_in[19];
    const float* b2_2 = (const float*)d_in[20];

    float* out = (float*)d_out;
    char* ws = (char*)d_ws;
    float* centers = (float*)(ws + 0);                 //  98304 B
    int* nbr0 = (int*)(ws + 98304);                    //  524288 B
    int* nbr1 = (int*)(ws + 622592);                   //  1048576 B
    int* nbr2 = (int*)(ws + 1671168);                  //  2097152 B
    int* nval = (int*)(ws + 3768320);                  //  98304 B
    // f16 transposed weights
    _Float16* w0t1 = (_Float16*)(ws + 3866624);        //  64*96  = 12288 B
    _Float16* w0t2 = (_Float16*)(ws + 3878912);        //  64*64  =  8192 B
    _Float16* w0t3 = (_Float16*)(ws + 3887104);        // 128*64  = 16384 B
    _Float16* w1t1 = (_Float16*)(ws + 3903488);        // 128*96  = 24576 B
    _Float16* w1t2 = (_Float16*)(ws + 3928064);        // 128*128 = 32768 B
    _Float16* w1t3 = (_Float16*)(ws + 3960832);        // 256*128 = 65536 B
    _Float16* w2t1 = (_Float16*)(ws + 4026368);
    _Float16* w2t2 = (_Float16*)(ws + 4050944);
    _Float16* w2t3 = (_Float16*)(ws + 4083712);        // end 4149248 B
    unsigned* prog = (unsigned*)(ws + 4149248);        // 8 x 128B progress lines
    // optional f16 copy of x (halves mlp gather traffic) — only if ws allows
    _Float16* xh = (ws_size >= (size_t)XH_OFF + XH_BYTES)
                       ? (_Float16*)(ws + XH_OFF) : (_Float16*)0;

    float* out_pos = out + (size_t)8192 * 640;
    float* out_batch = out_pos + (size_t)8192 * 3;

    hipMemsetAsync(prog, 0, NB * PROGSTRIDE * sizeof(unsigned), stream);

    PrepArgs pa;
    pa.src[0] = W0_0; pa.dst[0] = w0t1; pa.kr[0] = 67;  pa.kp[0] = 96;  pa.nc[0] = 64;
    pa.src[1] = W0_1; pa.dst[1] = w0t2; pa.kr[1] = 64;  pa.kp[1] = 64;  pa.nc[1] = 64;
    pa.src[2] = W0_2; pa.dst[2] = w0t3; pa.kr[2] = 64;  pa.kp[2] = 64;  pa.nc[2] = 128;
    pa.src[3] = W1_0; pa.dst[3] = w1t1; pa.kr[3] = 67;  pa.kp[3] = 96;  pa.nc[3] = 128;
    pa.src[4] = W1_1; pa.dst[4] = w1t2; pa.kr[4] = 128; pa.kp[4] = 128; pa.nc[4] = 128;
    pa.src[5] = W1_2; pa.dst[5] = w1t3; pa.kr[5] = 128; pa.kp[5] = 128; pa.nc[5] = 256;
    pa.src[6] = W2_0; pa.dst[6] = w2t1; pa.kr[6] = 67;  pa.kp[6] = 96;  pa.nc[6] = 128;
    pa.src[7] = W2_1; pa.dst[7] = w2t2; pa.kr[7] = 128; pa.kp[7] = 128; pa.nc[7] = 128;
    pa.src[8] = W2_2; pa.dst[8] = w2t3; pa.kr[8] = 128; pa.kp[8] = 128; pa.nc[8] = 256;

    fps_select_fused<<<dim3(256), dim3(512), 0, stream>>>(
        pos, centers, out_pos, out_batch, nbr0, nbr1, nbr2, nval, prog, pa,
        x, xh);

    MlpW ww;
    ww.w[0] = w0t1; ww.w[1] = w0t2; ww.w[2] = w0t3;
    ww.w[3] = w1t1; ww.w[4] = w1t2; ww.w[5] = w1t3;
    ww.w[6] = w2t1; ww.w[7] = w2t2; ww.w[8] = w2t3;
    ww.bias[0] = b0_0; ww.bias[1] = b0_1; ww.bias[2] = b0_2;
    ww.bias[3] = b1_0; ww.bias[4] = b1_1; ww.bias[5] = b1_2;
    ww.bias[6] = b2_0; ww.bias[7] = b2_1; ww.bias[8] = b2_2;

    // dynamic LDS = max over segs (single-buf + staged indices):
    // seg0: 64*104*2 + 64*72*2*2 + 4*128*4 + 64*4 + 4*4 = 34064
    // seg1: 64*104*2 + 64*136*2*2 + 2*256*4 + 64*4 + 2*4 = 50440  <- max
    // seg2: 64*104*2 + 64*136*2*2 + 1*256*4 + 64*4 + 1*4 = 49412
    // 50448 (16B-rounded) x 3 blocks/CU = 151344 <= 163840 LDS/CU.
    mlp_all<<<dim3(3072), dim3(256), 50448, stream>>>(
        x, xh, pos, centers, nbr0, nbr1, nbr2, nval, ww, out);
}